// Round 14
// baseline (132.713 us; speedup 1.0000x reference)
//
#include <hip/hip_runtime.h>

constexpr int Bn = 65536;   // rows (entity pairs)
constexpr int Cn = 512;     // relation classes

#define L2E 1.4426950408889634f
#define LN2 0.6931471805599453f

typedef float f32x4 __attribute__((ext_vector_type(4)));

// Global->LDS DMA: no VGPR destination, so the register allocator cannot
// serialize the pipeline. HW writes lane l's 16B to ldsbase + l*16.
__device__ __forceinline__ void gl2lds16(const float* g, float* l) {
  __builtin_amdgcn_global_load_lds(
      (const __attribute__((address_space(1))) void*)g,
      (__attribute__((address_space(3))) void*)l, 16, 0, 0);
}

__device__ __forceinline__ uint32_t lds_addr(const void* p) {
  return (uint32_t)(uintptr_t)(__attribute__((address_space(3))) const char*)(const char*)p;
}

// DPP lane-shuffle on the VALU pipe (zero DS-pipe traffic).
template <int Ctrl, int RowMask>
__device__ __forceinline__ float dpp_get(float x, float ident) {
  return __int_as_float(__builtin_amdgcn_update_dpp(
      __float_as_int(ident), __float_as_int(x), Ctrl, RowMask, 0xf, false));
}

// R11's proven geometry (8KB slots = 2 rows, depth-2, vmcnt(8)) at HIGHER
// occupancy: 1-wave blocks with 16KB LDS -> 10 blocks/CU (160KB LDS wall),
// 2.5 waves/SIMD (fixes R13's 1-wave/SIMD issue bubbles), 80KB in flight/CU.
// 2560 waves partition 32768 row-pairs exactly: 2048 waves x 13 + 512 x 12.
__global__ __launch_bounds__(64, 3) void matloss_main(
    const float* __restrict__ logits,
    const float* __restrict__ labels,
    double* __restrict__ acc) {

  const int lane = threadIdx.x & 63;
  const int w    = blockIdx.x;                  // 2560 single-wave blocks
  const int n    = (w < 2048) ? 13 : 12;        // rounds (2 rows each)
  const size_t pstart = (w < 2048) ? (size_t)w * 13
                                   : 26624 + (size_t)(w - 2048) * 12;

  __shared__ float smem[4096];                  // 16KB: 2 slots x 2048 f32
  float* slot0 = smem;                          // slot: rowA{lg lo,hi, lb lo,hi}
  float* slot1 = smem + 2048;                   //       rowB{same}  (8KB)

  auto stage = [&](size_t p, float* slot) {     // 8 vmem ops, 8KB, zero VGPRs
#pragma unroll
    for (int r = 0; r < 2; ++r) {
      const size_t row = 2 * p + r;
      const float* gl = logits + row * Cn + lane * 4;
      const float* gb = labels + row * Cn + lane * 4;
      float* s = slot + r * 1024;
      gl2lds16(gl,       s);
      gl2lds16(gl + 256, s + 256);
      gl2lds16(gb,       s + 512);
      gl2lds16(gb + 256, s + 768);
    }
  };

  stage(pstart,     slot0);                     // prologue: 16 loads in flight
  stage(pstart + 1, slot1);

  const uint32_t a0 = lds_addr(slot0) + lane * 16;
  const uint32_t a1 = a0 + 8192;

  float a_term = 0.f, a_cnt = 0.f, a_l2 = 0.f;

  for (int i = 0; i < n; ++i) {                 // dynamic trip count (12 or 13)
    if (i == n - 1) asm volatile("s_waitcnt vmcnt(0)" ::: "memory");
    else            asm volatile("s_waitcnt vmcnt(8)" ::: "memory");  // counted
    __builtin_amdgcn_sched_barrier(0);

    f32x4 q[8];                                 // rowA: lg lo/hi, lb lo/hi; rowB same
    const uint32_t va = (i & 1) ? a1 : a0;
    asm volatile("ds_read_b128 %0, %8\n\t"
                 "ds_read_b128 %1, %8 offset:1024\n\t"
                 "ds_read_b128 %2, %8 offset:2048\n\t"
                 "ds_read_b128 %3, %8 offset:3072\n\t"
                 "ds_read_b128 %4, %8 offset:4096\n\t"
                 "ds_read_b128 %5, %8 offset:5120\n\t"
                 "ds_read_b128 %6, %8 offset:6144\n\t"
                 "ds_read_b128 %7, %8 offset:7168"
                 : "=&v"(q[0]), "=&v"(q[1]), "=&v"(q[2]), "=&v"(q[3]),
                   "=&v"(q[4]), "=&v"(q[5]), "=&v"(q[6]), "=&v"(q[7])
                 : "v"(va));
    asm volatile("s_waitcnt lgkmcnt(0)" ::: "memory");
    __builtin_amdgcn_sched_barrier(0);          // rule #18: no consumer hoisting

    if (i + 2 < n) stage(pstart + i + 2, (i & 1) ? slot1 : slot0);

    float P[2], S[2], PM[2], CN[2], xz[2];
#pragma unroll
    for (int r = 0; r < 2; ++r) {               // both rows' chains interleave
      f32x4 xa = q[4 * r], xb = q[4 * r + 1], la = q[4 * r + 2], lc = q[4 * r + 3];
      float x[8] = {xa.x, xa.y, xa.z, xa.w, xb.x, xb.y, xb.z, xb.w};
      float l[8] = {la.x, la.y, la.z, la.w, lc.x, lc.y, lc.z, lc.w};
      xz[r] = __int_as_float(__builtin_amdgcn_readfirstlane(__float_as_int(x[0])));
      if (lane == 0) l[0] = 0.f;                // threshold class: label forced 0

      // P  = prod over positives of (1 + exp(-|x|));  PM = sum pos min(x,0)
      // S  = sum over negatives of exp(x)  (no-max LSE: |x| < ~6)
      float Pr = 1.f, Sr = 0.f, PMr = 0.f, CNr = 0.f;
#pragma unroll
      for (int k = 0; k < 8; ++k) {
        bool  pos = (l[k] != 0.f);
        float sel = pos ? -fabsf(x[k]) : x[k];
        float e   = __builtin_amdgcn_exp2f(sel * L2E);
        Pr  *= fmaf(l[k], e, 1.f);
        Sr  += pos ? 0.f : e;
        PMr  = fmaf(l[k], fminf(x[k], 0.f), PMr);
        CNr += l[k];
      }
      P[r] = Pr; S[r] = Sr; PM[r] = PMr; CN[r] = CNr;
    }

    // wave64 reduce on VALU pipe: 8 independent chains (2 rows x 4 vars)
#define RED8(CTRL, RM)                                        \
    _Pragma("unroll")                                         \
    for (int r = 0; r < 2; ++r) {                             \
      S[r]  += dpp_get<CTRL, RM>(S[r],  0.f);                 \
      CN[r] += dpp_get<CTRL, RM>(CN[r], 0.f);                 \
      PM[r] += dpp_get<CTRL, RM>(PM[r], 0.f);                 \
      P[r]  *= dpp_get<CTRL, RM>(P[r],  1.f);                 \
    }
    RED8(0x111, 0xf)                            // row_shr:1
    RED8(0x112, 0xf)                            // row_shr:2
    RED8(0x114, 0xf)                            // row_shr:4
    RED8(0x118, 0xf)                            // row_shr:8
    RED8(0x142, 0xa)                            // row_bcast:15 (rows 1,3)
    RED8(0x143, 0xc)                            // row_bcast:31 (rows 2,3)
#undef RED8

#pragma unroll
    for (int r = 0; r < 2; ++r) {
      float Sw  = __int_as_float(__builtin_amdgcn_readlane(__float_as_int(S[r]),  63));
      float CNw = __int_as_float(__builtin_amdgcn_readlane(__float_as_int(CN[r]), 63));
      float PMw = __int_as_float(__builtin_amdgcn_readlane(__float_as_int(PM[r]), 63));
      float Pw  = __int_as_float(__builtin_amdgcn_readlane(__float_as_int(P[r]),  63));

      a_l2 += LN2 * __builtin_amdgcn_logf(Sw) - xz[r];   // lse - x0
      if (CNw > 0.f) {                          // wave-uniform branch
        float t0  = __builtin_amdgcn_exp2f(-fabsf(xz[r]) * L2E);
        float ls0 = fminf(-xz[r], 0.f) - LN2 * __builtin_amdgcn_logf(1.f + t0);
        a_term += ls0 + PMw - LN2 * __builtin_amdgcn_logf(Pw);
        a_cnt  += 1.f + CNw;
      }
    }
  }

  if (lane == 0) {                              // 1 wave/block: no LDS reduce
    atomicAdd(&acc[0], (double)a_term);
    atomicAdd(&acc[1], (double)a_cnt);
    atomicAdd(&acc[2], (double)a_l2);
  }
}

__global__ void matloss_final(const double* __restrict__ acc, float* __restrict__ out) {
  out[0] = (float)(-acc[0] / acc[1] + acc[2] / (double)Bn);
}

extern "C" void kernel_launch(void* const* d_in, const int* in_sizes, int n_in,
                              void* d_out, int out_size, void* d_ws, size_t ws_size,
                              hipStream_t stream) {
  const float* logits = (const float*)d_in[0];
  const float* labels = (const float*)d_in[1];
  float* out = (float*)d_out;
  double* acc = (double*)d_ws;

  hipMemsetAsync(d_ws, 0, 3 * sizeof(double), stream);  // zero accumulators (capture-safe)
  matloss_main<<<2560, 64, 0, stream>>>(logits, labels, acc);
  matloss_final<<<1, 1, 0, stream>>>(acc, out);
}

// Round 15
// 59.611 us; speedup vs baseline: 2.2263x; 2.2263x over previous
//
#include <hip/hip_runtime.h>

constexpr int Bn = 65536;   // rows (entity pairs)
constexpr int Cn = 512;     // relation classes

#define L2E 1.4426950408889634f
#define LN2 0.6931471805599453f

typedef float f32x4 __attribute__((ext_vector_type(4)));

// Global->LDS DMA: no VGPR destination, so the register allocator cannot
// serialize the pipeline. HW writes lane l's 16B to ldsbase + l*16.
__device__ __forceinline__ void gl2lds16(const float* g, float* l) {
  __builtin_amdgcn_global_load_lds(
      (const __attribute__((address_space(1))) void*)g,
      (__attribute__((address_space(3))) void*)l, 16, 0, 0);
}

__device__ __forceinline__ uint32_t lds_addr(const void* p) {
  return (uint32_t)(uintptr_t)(__attribute__((address_space(3))) const char*)(const char*)p;
}

// DPP lane-shuffle on the VALU pipe (zero DS-pipe traffic).
template <int Ctrl, int RowMask>
__device__ __forceinline__ float dpp_get(float x, float ident) {
  return __int_as_float(__builtin_amdgcn_update_dpp(
      __float_as_int(ident), __float_as_int(x), Ctrl, RowMask, 0xf, false));
}

// BEST CONFIG (R11, 59.4us): 2 rows/iter, 8KB slots, depth-2 double buffer,
// vmcnt(8) counted waits, 512 blocks x 4 waves x 64KB LDS = 2 blocks/CU,
// 8 waves/CU, DPP wave-reduce on VALU pipe. Response-surface probes in every
// direction (slot size 2/4/16KB, waves 4..32/CU, contiguity, VGPR-path
// pipelines) are all worse or flat: service-rate ceiling ~4.5 TB/s combined
// HBM+L3 read for this read-once pattern.
__global__ __launch_bounds__(256, 2) void matloss_main(
    const float* __restrict__ logits,
    const float* __restrict__ labels,
    double* __restrict__ acc) {

  const int lane = threadIdx.x & 63;
  const int wib  = threadIdx.x >> 6;
  const int gw   = blockIdx.x * 4 + wib;        // 2048 waves, all resident
  constexpr int NW = 2048;                      // row stride
  constexpr int IT = 16;                        // iterations (2 rows each)

  __shared__ float smem[4 * 2 * 2048];          // 64KB: [wave][slot][2048 f32]
  float* slot0 = &smem[wib * 4096];             // slot: rowA{lg 1K x2, lb 1K x2}
  float* slot1 = slot0 + 2048;                  //       rowB{same}  (8KB total)

  auto stage = [&](int i, float* slot) {        // 8 vmem ops, 8KB, zero VGPRs
#pragma unroll
    for (int r = 0; r < 2; ++r) {
      const size_t row = (size_t)(gw + (2 * i + r) * NW);
      const float* gl = logits + row * Cn + lane * 4;
      const float* gb = labels + row * Cn + lane * 4;
      float* s = slot + r * 1024;
      gl2lds16(gl,       s);
      gl2lds16(gl + 256, s + 256);
      gl2lds16(gb,       s + 512);
      gl2lds16(gb + 256, s + 768);
    }
  };

  stage(0, slot0);                              // prologue: 16 loads in flight
  stage(1, slot1);

  const uint32_t a0 = lds_addr(slot0) + lane * 16;
  const uint32_t a1 = a0 + 8192;

  float a_term = 0.f, a_cnt = 0.f, a_l2 = 0.f;

#pragma unroll
  for (int i = 0; i < IT; ++i) {
    if (i == IT - 1) asm volatile("s_waitcnt vmcnt(0)" ::: "memory");
    else             asm volatile("s_waitcnt vmcnt(8)" ::: "memory");  // counted, never 0
    __builtin_amdgcn_sched_barrier(0);

    f32x4 q[8];                                 // rowA: lg lo/hi, lb lo/hi; rowB: same
    const uint32_t va = (i & 1) ? a1 : a0;
    asm volatile("ds_read_b128 %0, %8\n\t"
                 "ds_read_b128 %1, %8 offset:1024\n\t"
                 "ds_read_b128 %2, %8 offset:2048\n\t"
                 "ds_read_b128 %3, %8 offset:3072\n\t"
                 "ds_read_b128 %4, %8 offset:4096\n\t"
                 "ds_read_b128 %5, %8 offset:5120\n\t"
                 "ds_read_b128 %6, %8 offset:6144\n\t"
                 "ds_read_b128 %7, %8 offset:7168"
                 : "=&v"(q[0]), "=&v"(q[1]), "=&v"(q[2]), "=&v"(q[3]),
                   "=&v"(q[4]), "=&v"(q[5]), "=&v"(q[6]), "=&v"(q[7])
                 : "v"(va));
    asm volatile("s_waitcnt lgkmcnt(0)" ::: "memory");
    __builtin_amdgcn_sched_barrier(0);          // rule #18: no consumer hoisting

    if (i + 2 < IT) stage(i + 2, (i & 1) ? slot1 : slot0);  // refill under compute

    float P[2], S[2], PM[2], CN[2], xz[2];
#pragma unroll
    for (int r = 0; r < 2; ++r) {               // both rows' chains interleave
      f32x4 xa = q[4 * r], xb = q[4 * r + 1], la = q[4 * r + 2], lc = q[4 * r + 3];
      float x[8] = {xa.x, xa.y, xa.z, xa.w, xb.x, xb.y, xb.z, xb.w};
      float l[8] = {la.x, la.y, la.z, la.w, lc.x, lc.y, lc.z, lc.w};
      xz[r] = __int_as_float(__builtin_amdgcn_readfirstlane(__float_as_int(x[0])));
      if (lane == 0) l[0] = 0.f;                // threshold class: label forced 0

      // P  = prod over positives of (1 + exp(-|x|));  PM = sum pos min(x,0)
      // S  = sum over negatives of exp(x)  (no-max LSE: |x| < ~6)
      float Pr = 1.f, Sr = 0.f, PMr = 0.f, CNr = 0.f;
#pragma unroll
      for (int k = 0; k < 8; ++k) {
        bool  pos = (l[k] != 0.f);
        float sel = pos ? -fabsf(x[k]) : x[k];
        float e   = __builtin_amdgcn_exp2f(sel * L2E);
        Pr  *= fmaf(l[k], e, 1.f);
        Sr  += pos ? 0.f : e;
        PMr  = fmaf(l[k], fminf(x[k], 0.f), PMr);
        CNr += l[k];
      }
      P[r] = Pr; S[r] = Sr; PM[r] = PMr; CN[r] = CNr;
    }

    // wave64 reduce on VALU pipe: 8 independent chains (2 rows x 4 vars)
#define RED8(CTRL, RM)                                        \
    _Pragma("unroll")                                         \
    for (int r = 0; r < 2; ++r) {                             \
      S[r]  += dpp_get<CTRL, RM>(S[r],  0.f);                 \
      CN[r] += dpp_get<CTRL, RM>(CN[r], 0.f);                 \
      PM[r] += dpp_get<CTRL, RM>(PM[r], 0.f);                 \
      P[r]  *= dpp_get<CTRL, RM>(P[r],  1.f);                 \
    }
    RED8(0x111, 0xf)                            // row_shr:1
    RED8(0x112, 0xf)                            // row_shr:2
    RED8(0x114, 0xf)                            // row_shr:4
    RED8(0x118, 0xf)                            // row_shr:8
    RED8(0x142, 0xa)                            // row_bcast:15 (rows 1,3)
    RED8(0x143, 0xc)                            // row_bcast:31 (rows 2,3)
#undef RED8

#pragma unroll
    for (int r = 0; r < 2; ++r) {
      float Sw  = __int_as_float(__builtin_amdgcn_readlane(__float_as_int(S[r]),  63));
      float CNw = __int_as_float(__builtin_amdgcn_readlane(__float_as_int(CN[r]), 63));
      float PMw = __int_as_float(__builtin_amdgcn_readlane(__float_as_int(PM[r]), 63));
      float Pw  = __int_as_float(__builtin_amdgcn_readlane(__float_as_int(P[r]),  63));

      a_l2 += LN2 * __builtin_amdgcn_logf(Sw) - xz[r];   // lse - x0
      if (CNw > 0.f) {                          // wave-uniform branch
        float t0  = __builtin_amdgcn_exp2f(-fabsf(xz[r]) * L2E);
        float ls0 = fminf(-xz[r], 0.f) - LN2 * __builtin_amdgcn_logf(1.f + t0);
        a_term += ls0 + PMw - LN2 * __builtin_amdgcn_logf(Pw);
        a_cnt  += 1.f + CNw;
      }
    }
  }

  // block reduce: reuse staging LDS (all staging reads done; barrier first)
  __syncthreads();
  if (lane == 0) { smem[wib] = a_term; smem[4 + wib] = a_cnt; smem[8 + wib] = a_l2; }
  __syncthreads();
  if (threadIdx.x == 0) {
    atomicAdd(&acc[0], (double)(smem[0] + smem[1] + smem[2]  + smem[3]));
    atomicAdd(&acc[1], (double)(smem[4] + smem[5] + smem[6]  + smem[7]));
    atomicAdd(&acc[2], (double)(smem[8] + smem[9] + smem[10] + smem[11]));
  }
}

__global__ void matloss_final(const double* __restrict__ acc, float* __restrict__ out) {
  out[0] = (float)(-acc[0] / acc[1] + acc[2] / (double)Bn);
}

extern "C" void kernel_launch(void* const* d_in, const int* in_sizes, int n_in,
                              void* d_out, int out_size, void* d_ws, size_t ws_size,
                              hipStream_t stream) {
  const float* logits = (const float*)d_in[0];
  const float* labels = (const float*)d_in[1];
  float* out = (float*)d_out;
  double* acc = (double*)d_ws;

  hipMemsetAsync(d_ws, 0, 3 * sizeof(double), stream);  // zero accumulators (capture-safe)
  matloss_main<<<512, 256, 0, stream>>>(logits, labels, acc);
  matloss_final<<<1, 1, 0, stream>>>(acc, out);
}